// Round 3
// baseline (311.056 us; speedup 1.0000x reference)
//
#include <hip/hip_runtime.h>
#include <hip/hip_bf16.h>

// Problem constants (B=8192, D=512 from reference setup_inputs)
#define BN_ 8192
#define DK_ 512
#define TEMP_INV 14.2857142857142857f   // 1/0.07
#define LOG2E_ 1.44269504088896f
#define MAXOFF 15.0f                    // fixed lse offset; |sim| < 14.29 (unit vectors)

typedef __bf16 bf16x8 __attribute__((ext_vector_type(8)));
typedef float f32x4 __attribute__((ext_vector_type(4)));

__device__ inline unsigned short f2bf(float f) {
    unsigned u = __float_as_uint(f);
    return (unsigned short)((u + 0x7FFFu + ((u >> 16) & 1u)) >> 16);
}

// ---------------- Kernel 1: L2-normalize rows, write bf16 ----------------
__global__ __launch_bounds__(256) void norm_kernel(const float* __restrict__ emb,
                                                   unsigned short* __restrict__ ebf) {
    const int row  = blockIdx.x * 4 + (threadIdx.x >> 6);
    const int lane = threadIdx.x & 63;
    const float4* src = reinterpret_cast<const float4*>(emb + (size_t)row * DK_);
    float4 v0 = src[lane];
    float4 v1 = src[lane + 64];
    float ss = v0.x*v0.x + v0.y*v0.y + v0.z*v0.z + v0.w*v0.w
             + v1.x*v1.x + v1.y*v1.y + v1.z*v1.z + v1.w*v1.w;
#pragma unroll
    for (int off = 1; off < 64; off <<= 1) ss += __shfl_xor(ss, off, 64);
    const float scale = 1.0f / fmaxf(sqrtf(ss), 1e-12f);
    uint2 o0, o1;
    o0.x = (unsigned)f2bf(v0.x * scale) | ((unsigned)f2bf(v0.y * scale) << 16);
    o0.y = (unsigned)f2bf(v0.z * scale) | ((unsigned)f2bf(v0.w * scale) << 16);
    o1.x = (unsigned)f2bf(v1.x * scale) | ((unsigned)f2bf(v1.y * scale) << 16);
    o1.y = (unsigned)f2bf(v1.z * scale) | ((unsigned)f2bf(v1.w * scale) << 16);
    uint2* dst = reinterpret_cast<uint2*>(ebf + (size_t)row * DK_);
    dst[lane]      = o0;
    dst[lane + 64] = o1;
}

// ---------------- Kernel 2: fused 128x128 MFMA tile + row reductions ----------------
// grid (64,64); 256 threads = 4 waves, each wave a 64x64 quadrant (4x4 frags 16x16x32).
// Mask tile (64KB of int) is bit-packed in-loop: 2 coalesced int4 loads/thread/iter ->
// 64 bits/thread in 2 VGPRs -> 2KB LDS bit-tile consumed by the epilogue.
__global__ __launch_bounds__(256) void infonce_main(
    const unsigned short* __restrict__ ebf,
    const int* __restrict__ mask,
    float* __restrict__ se, float* __restrict__ ps, float* __restrict__ ct) {

    __shared__ unsigned short As[128 * 64];
    __shared__ unsigned short Bs[128 * 64];
    __shared__ uint2 mtile[256];      // 128 rows x 2 halves of 64 mask bits
    __shared__ float red3[3][128];

    const int t    = threadIdx.x;
    const int lane = t & 63;
    const int wid  = t >> 6;
    const int wr   = wid >> 1;
    const int wc   = wid & 1;
    const int rb   = blockIdx.x;
    const int cb   = blockIdx.y;

    if (t < 128) { red3[0][t] = 0.f; red3[1][t] = 0.f; red3[2][t] = 0.f; }

    f32x4 acc[4][4] = {};

    // ebf staging map: thread t -> row t/8 (of 32), 16B chunk (t%8) within 64-elem k-row
    const int sr = t >> 3;
    const int sc = (t & 7) * 8;
    const size_t arow0 = (size_t)(rb * 128 + sr) * DK_ + sc;
    const size_t brow0 = (size_t)(cb * 128 + sr) * DK_ + sc;

    // mask staging: thread t -> local row t>>1, 64-col half t&1 (16 int4 total)
    const int4* mrow = reinterpret_cast<const int4*>(
        mask + (size_t)(rb * 128 + (t >> 1)) * BN_ + cb * 128 + (t & 1) * 64);
    uint2 mbits; mbits.x = 0u; mbits.y = 0u;
    int4 mA = mrow[0];            // pair 0 in flight before the loop
    int4 mB = mrow[1];

    const int r16 = lane & 15;
    const int kg  = (lane >> 4) * 8;

#pragma unroll
    for (int kt = 0; kt < 8; ++kt) {
        const int k0 = kt * 64;
#pragma unroll
        for (int s = 0; s < 4; ++s) {
            __builtin_amdgcn_global_load_lds(
                (const __attribute__((address_space(1))) void*)(ebf + arow0 + (size_t)s * 32 * DK_ + k0),
                (__attribute__((address_space(3))) void*)(As + s * 2048 + t * 8),
                16, 0, 0);
        }
#pragma unroll
        for (int s = 0; s < 4; ++s) {
            __builtin_amdgcn_global_load_lds(
                (const __attribute__((address_space(1))) void*)(ebf + brow0 + (size_t)s * 32 * DK_ + k0),
                (__attribute__((address_space(3))) void*)(Bs + s * 2048 + t * 8),
                16, 0, 0);
        }

        // convert mask pair kt (loaded one iter ago, latency fully spanned)
        {
            unsigned b8 = (unsigned)(mA.x != 0)        | ((unsigned)(mA.y != 0) << 1)
                        | ((unsigned)(mA.z != 0) << 2) | ((unsigned)(mA.w != 0) << 3)
                        | ((unsigned)(mB.x != 0) << 4) | ((unsigned)(mB.y != 0) << 5)
                        | ((unsigned)(mB.z != 0) << 6) | ((unsigned)(mB.w != 0) << 7);
            if (kt < 4) mbits.x |= b8 << (kt * 8);
            else        mbits.y |= b8 << ((kt - 4) * 8);
        }
        if (kt < 7) { mA = mrow[(kt + 1) * 2]; mB = mrow[(kt + 1) * 2 + 1]; }
        else        { mtile[t] = mbits; }   // final bits -> LDS; barriers below order it

        __syncthreads();

        const bf16x8* Asv = reinterpret_cast<const bf16x8*>(As);
#pragma unroll
        for (int ks = 0; ks < 2; ++ks) {
            bf16x8 af[4], bfr[4];
#pragma unroll
            for (int fm = 0; fm < 4; ++fm)
                af[fm] = *reinterpret_cast<const bf16x8*>(As + (wr * 64 + fm * 16 + r16) * 64 + ks * 32 + kg);
#pragma unroll
            for (int fn = 0; fn < 4; ++fn)
                bfr[fn] = *reinterpret_cast<const bf16x8*>(Bs + (wc * 64 + fn * 16 + r16) * 64 + ks * 32 + kg);
#pragma unroll
            for (int fm = 0; fm < 4; ++fm)
#pragma unroll
                for (int fn = 0; fn < 4; ++fn)
                    acc[fm][fn] = __builtin_amdgcn_mfma_f32_16x16x32_bf16(af[fm], bfr[fn], acc[fm][fn], 0, 0, 0);
        }
        __syncthreads();
    }

    // ---- epilogue: per-row partials {sum exp(sim-15), pos_sum, count} ----
    // C/D layout (16x16x32): col = lane&15, row = (lane>>4)*4 + reg
    const int colBase = cb * 128 + wc * 64 + (lane & 15);
    const int c0      = cb * 128 + wc * 64;
    const float C1 = TEMP_INV * LOG2E_;
    const float C2 = -MAXOFF * LOG2E_;
#pragma unroll
    for (int fm = 0; fm < 4; ++fm) {
#pragma unroll
        for (int q = 0; q < 4; ++q) {
            const int li = wr * 64 + fm * 16 + ((lane >> 4) << 2) + q;  // local row
            const int i  = rb * 128 + li;                               // global row
            const uint2 mb = mtile[li * 2 + wc];   // broadcast to 16 lanes
            float lsep = 0.f, posp = 0.f;
#pragma unroll
            for (int fn = 0; fn < 4; ++fn) {
                const int j = colBase + fn * 16;
                const float a = acc[fm][fn][q];
                const bool diag = (i == j);
                const float ex = diag ? 0.0f : exp2f(fmaf(a, C1, C2));
                lsep += ex;
                const unsigned w = (fn < 2) ? mb.x : mb.y;
                const bool p = (((w >> ((fn & 1) * 16 + (lane & 15))) & 1u) != 0u) && (!diag);
                posp += p ? a * TEMP_INV : 0.0f;
            }
#pragma unroll
            for (int off = 1; off < 16; off <<= 1) {
                lsep += __shfl_xor(lsep, off, 64);
                posp += __shfl_xor(posp, off, 64);
            }
            if ((lane & 15) == 0) {
                float cnt = (float)(__popc(mb.x) + __popc(mb.y));
                if (i >= c0 && i < c0 + 64) {      // exclude diagonal from count
                    const int d = i - c0;
                    cnt -= (float)((d < 32 ? (mb.x >> d) : (mb.y >> (d - 32))) & 1u);
                }
                atomicAdd(&red3[0][li], lsep);     // ds_add_f32 cross-wave merge
                atomicAdd(&red3[1][li], posp);
                atomicAdd(&red3[2][li], cnt);
            }
        }
    }
    __syncthreads();
    if (t < 128) {
        const int i = rb * 128 + t;
        atomicAdd(&se[i], red3[0][t]);
        atomicAdd(&ps[i], red3[1][t]);
        atomicAdd(&ct[i], red3[2][t]);
    }
}

// ---------------- Kernel 3: finalize scalar loss (32 blocks) ----------------
__global__ __launch_bounds__(256) void finalize_kernel(const float* __restrict__ se,
                                                       const float* __restrict__ ps,
                                                       const float* __restrict__ ct,
                                                       float* __restrict__ out) {
    __shared__ float red[256];
    const int t = threadIdx.x;
    const int i = blockIdx.x * 256 + t;
    const float lse = logf(se[i]) + MAXOFF;
    red[t] = lse - ps[i] / fmaxf(ct[i], 1.0f);
    __syncthreads();
    for (int s = 128; s > 0; s >>= 1) {
        if (t < s) red[t] += red[t + s];
        __syncthreads();
    }
    if (t == 0) atomicAdd(out, red[0] * (1.0f / (float)BN_));
}

extern "C" void kernel_launch(void* const* d_in, const int* in_sizes, int n_in,
                              void* d_out, int out_size, void* d_ws, size_t ws_size,
                              hipStream_t stream) {
    const float* emb  = (const float*)d_in[0];
    const int*   mask = (const int*)d_in[1];
    float* out = (float*)d_out;

    char* ws = (char*)d_ws;
    unsigned short* ebf = (unsigned short*)ws;                  // 8192*512*2 = 8 MB
    float* se = (float*)(ws + (size_t)BN_ * DK_ * 2);
    float* ps = se + BN_;
    float* ct = ps + BN_;

    hipMemsetAsync(se, 0, (size_t)3 * BN_ * sizeof(float), stream);
    hipMemsetAsync(out, 0, sizeof(float), stream);
    norm_kernel<<<BN_ / 4, 256, 0, stream>>>(emb, ebf);
    infonce_main<<<dim3(64, 64), 256, 0, stream>>>(ebf, mask, se, ps, ct);
    finalize_kernel<<<BN_ / 256, 256, 0, stream>>>(se, ps, ct, out);
}

// Round 4
// 200.003 us; speedup vs baseline: 1.5553x; 1.5553x over previous
//
#include <hip/hip_runtime.h>
#include <hip/hip_bf16.h>

// Problem constants (B=8192, D=512 from reference setup_inputs)
#define BN_ 8192
#define DK_ 512
#define TEMP_INV 14.2857142857142857f   // 1/0.07
#define LOG2E_ 1.44269504088896f
#define MAXOFF 15.0f                    // fixed lse offset; |sim| < 14.29 (unit vectors)

typedef __bf16 bf16x8 __attribute__((ext_vector_type(8)));
typedef float f32x4 __attribute__((ext_vector_type(4)));

__device__ inline unsigned short f2bf(float f) {
    unsigned u = __float_as_uint(f);
    return (unsigned short)((u + 0x7FFFu + ((u >> 16) & 1u)) >> 16);
}

// ---------- Kernel 1: fused {L2-normalize -> bf16} + {mask -> bit-pack} ----------
// blocks 0..2047: norm (4 rows each). blocks 2048..10239: pack one mask row each.
__global__ __launch_bounds__(256) void normpack_kernel(
    const float* __restrict__ emb, const int* __restrict__ mask,
    unsigned short* __restrict__ ebf, unsigned long long* __restrict__ pk) {
    const int t = threadIdx.x;
    if (blockIdx.x < 2048) {
        const int row  = blockIdx.x * 4 + (t >> 6);
        const int lane = t & 63;
        const float4* src = reinterpret_cast<const float4*>(emb + (size_t)row * DK_);
        float4 v0 = src[lane];
        float4 v1 = src[lane + 64];
        float ss = v0.x*v0.x + v0.y*v0.y + v0.z*v0.z + v0.w*v0.w
                 + v1.x*v1.x + v1.y*v1.y + v1.z*v1.z + v1.w*v1.w;
#pragma unroll
        for (int off = 1; off < 64; off <<= 1) ss += __shfl_xor(ss, off, 64);
        const float scale = 1.0f / fmaxf(sqrtf(ss), 1e-12f);
        uint2 o0, o1;
        o0.x = (unsigned)f2bf(v0.x * scale) | ((unsigned)f2bf(v0.y * scale) << 16);
        o0.y = (unsigned)f2bf(v0.z * scale) | ((unsigned)f2bf(v0.w * scale) << 16);
        o1.x = (unsigned)f2bf(v1.x * scale) | ((unsigned)f2bf(v1.y * scale) << 16);
        o1.y = (unsigned)f2bf(v1.z * scale) | ((unsigned)f2bf(v1.w * scale) << 16);
        uint2* dst = reinterpret_cast<uint2*>(ebf + (size_t)row * DK_);
        dst[lane]      = o0;
        dst[lane + 64] = o1;
    } else {
        const int p    = blockIdx.x - 2048;          // mask row
        const int lane = t & 63;
        const int w    = t >> 6;
        const int* src = mask + (size_t)p * BN_;
#pragma unroll 4
        for (int it = 0; it < 32; ++it) {
            const int v = src[it * 256 + t];          // fully coalesced 1KB/wave-instr
            const unsigned long long bal = __ballot(v != 0);
            if (lane == 0) pk[(size_t)p * 128 + it * 4 + w] = bal;
        }
    }
}

// ---------- Kernel 2: symmetric 128x128 MFMA tiles (cb >= rb) + row/col reductions ----
// grid 2080; 256 threads = 4 waves (wr,wc), each a 64x64 quadrant of 16x16x32 frags.
// Mask bits come from the packed buffer, staged to LDS before the K-loop (hidden).
__global__ __launch_bounds__(256) void infonce_main(
    const unsigned short* __restrict__ ebf,
    const unsigned* __restrict__ pk,
    float* __restrict__ se, float* __restrict__ ps, float* __restrict__ ct) {

    __shared__ unsigned short As[128 * 64];
    __shared__ unsigned short Bs[128 * 64];
    __shared__ uint4 pmS[256];        // [0..127] rows of rb-block (cols cb*128..+127)
                                      // [128..255] rows of cb-block (cols rb*128..+127)
    __shared__ float red3[3][128];    // row-partial accumulators (rb-block rows)
    __shared__ float redc[3][128];    // col-partial accumulators (cb-block rows)

    const int t    = threadIdx.x;
    const int lane = t & 63;
    const int wid  = t >> 6;
    const int wr   = wid >> 1;
    const int wc   = wid & 1;

    // triangular decode: bid -> (rb, cb) with cb >= rb; base(r) = 64r - r(r-1)/2
    const int bid = blockIdx.x;
    int rb = (int)((129.0f - sqrtf(16641.0f - 8.0f * (float)bid)) * 0.5f);
    while (64 * (rb + 1) - ((rb + 1) * rb) / 2 <= bid) ++rb;
    while (64 * rb - (rb * (rb - 1)) / 2 > bid) --rb;
    const int cb = rb + (bid - (64 * rb - (rb * (rb - 1)) / 2));
    const bool offd = (rb != cb);

    if (t < 128) {
        red3[0][t] = 0.f; red3[1][t] = 0.f; red3[2][t] = 0.f;
        redc[0][t] = 0.f; redc[1][t] = 0.f; redc[2][t] = 0.f;
    }
    // stage packed mask bits (4KB): one uint4 per thread, issued before the K-loop
    const uint4* pk4 = reinterpret_cast<const uint4*>(pk);
    pmS[t] = (t < 128) ? pk4[(size_t)(rb * 128 + t) * 64 + cb]
                       : pk4[(size_t)(cb * 128 + (t - 128)) * 64 + rb];

    f32x4 acc[4][4] = {};

    // ebf staging map: thread t -> row t/8 (of 32), 16B chunk (t%8) within 64-elem k-row
    const int sr = t >> 3;
    const int sc = (t & 7) * 8;
    const size_t arow0 = (size_t)(rb * 128 + sr) * DK_ + sc;
    const size_t brow0 = (size_t)(cb * 128 + sr) * DK_ + sc;

    const int r16 = lane & 15;
    const int kg  = (lane >> 4) * 8;

#pragma unroll
    for (int kt = 0; kt < 8; ++kt) {
        const int k0 = kt * 64;
#pragma unroll
        for (int s = 0; s < 4; ++s) {
            __builtin_amdgcn_global_load_lds(
                (const __attribute__((address_space(1))) void*)(ebf + arow0 + (size_t)s * 32 * DK_ + k0),
                (__attribute__((address_space(3))) void*)(As + s * 2048 + t * 8),
                16, 0, 0);
        }
#pragma unroll
        for (int s = 0; s < 4; ++s) {
            __builtin_amdgcn_global_load_lds(
                (const __attribute__((address_space(1))) void*)(ebf + brow0 + (size_t)s * 32 * DK_ + k0),
                (__attribute__((address_space(3))) void*)(Bs + s * 2048 + t * 8),
                16, 0, 0);
        }
        __syncthreads();

#pragma unroll
        for (int ks = 0; ks < 2; ++ks) {
            bf16x8 af[4], bfr[4];
#pragma unroll
            for (int fm = 0; fm < 4; ++fm)
                af[fm] = *reinterpret_cast<const bf16x8*>(As + (wr * 64 + fm * 16 + r16) * 64 + ks * 32 + kg);
#pragma unroll
            for (int fn = 0; fn < 4; ++fn)
                bfr[fn] = *reinterpret_cast<const bf16x8*>(Bs + (wc * 64 + fn * 16 + r16) * 64 + ks * 32 + kg);
#pragma unroll
            for (int fm = 0; fm < 4; ++fm)
#pragma unroll
                for (int fn = 0; fn < 4; ++fn)
                    acc[fm][fn] = __builtin_amdgcn_mfma_f32_16x16x32_bf16(af[fm], bfr[fn], acc[fm][fn], 0, 0, 0);
        }
        __syncthreads();
    }

    // ---- epilogue ----
    // C/D layout (16x16x32): col = lane&15, row = (lane>>4)*4 + reg
    const float C1 = TEMP_INV * LOG2E_;
    const float C2 = -MAXOFF * LOG2E_;
    const int c0 = cb * 128 + wc * 64;

    // per-lane column mask words (rows of this wave's quadrant), for the col part
    uint2 cw[4];
    if (offd) {
#pragma unroll
        for (int fn = 0; fn < 4; ++fn) {
            const int lj = wc * 64 + fn * 16 + (lane & 15);
            const uint4 v = pmS[128 + lj];
            cw[fn].x = wr ? v.z : v.x;   // bits for i_local in [wr*64, wr*64+32)
            cw[fn].y = wr ? v.w : v.y;   // bits for i_local in [wr*64+32, wr*64+64)
        }
    }
    float colL[4] = {0.f, 0.f, 0.f, 0.f};
    float colP[4] = {0.f, 0.f, 0.f, 0.f};

#pragma unroll
    for (int fm = 0; fm < 4; ++fm) {
#pragma unroll
        for (int q = 0; q < 4; ++q) {
            const int li = wr * 64 + fm * 16 + ((lane >> 4) << 2) + q;
            const int i  = rb * 128 + li;
            const uint4 rv = pmS[li];
            const unsigned r0 = wc ? rv.z : rv.x;   // this wave's 64-col window
            const unsigned r1 = wc ? rv.w : rv.y;
            float lsep = 0.f, posp = 0.f;
#pragma unroll
            for (int fn = 0; fn < 4; ++fn) {
                const int j = c0 + fn * 16 + (lane & 15);
                const float a = acc[fm][fn][q];
                const bool diag = (i == j);
                const float ex = diag ? 0.0f : exp2f(fmaf(a, C1, C2));
                lsep += ex;
                const unsigned w = (fn < 2) ? r0 : r1;
                const bool p = (((w >> ((fn & 1) * 16 + (lane & 15))) & 1u) != 0u) && (!diag);
                posp += p ? a * TEMP_INV : 0.0f;
                if (offd) {
                    colL[fn] += ex;   // symmetric: sim(j,i) == sim(i,j); i != j always
                    const unsigned cwv = (fm < 2) ? cw[fn].x : cw[fn].y;
                    const int cbit = (fm & 1) * 16 + ((lane >> 4) << 2) + q;
                    colP[fn] += ((cwv >> cbit) & 1u) ? a * TEMP_INV : 0.0f;
                }
            }
#pragma unroll
            for (int off = 1; off < 16; off <<= 1) {
                lsep += __shfl_xor(lsep, off, 64);
                posp += __shfl_xor(posp, off, 64);
            }
            if ((lane & 15) == 0) {
                float cnt = (float)(__popc(r0) + __popc(r1));
                if (i >= c0 && i < c0 + 64) {        // remove diagonal from count
                    const int d = i - c0;
                    cnt -= (float)((d < 32 ? (r0 >> d) : (r1 >> (d - 32))) & 1u);
                }
                atomicAdd(&red3[0][li], lsep);       // ds_add_f32 cross-wave merge
                atomicAdd(&red3[1][li], posp);
                atomicAdd(&red3[2][li], cnt);
            }
        }
    }

    if (offd) {
#pragma unroll
        for (int fn = 0; fn < 4; ++fn) {
            float L = colL[fn], P = colP[fn];
            L += __shfl_xor(L, 16, 64); L += __shfl_xor(L, 32, 64);
            P += __shfl_xor(P, 16, 64); P += __shfl_xor(P, 32, 64);
            if ((lane >> 4) == 0) {                  // lanes 0..15
                const int lj = wc * 64 + fn * 16 + lane;
                const float cnt = (float)(__popc(cw[fn].x) + __popc(cw[fn].y));
                atomicAdd(&redc[0][lj], L);
                atomicAdd(&redc[1][lj], P);
                atomicAdd(&redc[2][lj], cnt);
            }
        }
    }
    __syncthreads();
    if (t < 128) {
        const int i = rb * 128 + t;
        atomicAdd(&se[i], red3[0][t]);
        atomicAdd(&ps[i], red3[1][t]);
        atomicAdd(&ct[i], red3[2][t]);
    } else if (offd) {
        const int j = cb * 128 + (t - 128);
        atomicAdd(&se[j], redc[0][t - 128]);
        atomicAdd(&ps[j], redc[1][t - 128]);
        atomicAdd(&ct[j], redc[2][t - 128]);
    }
}

// ---------------- Kernel 3: finalize scalar loss (32 blocks) ----------------
__global__ __launch_bounds__(256) void finalize_kernel(const float* __restrict__ se,
                                                       const float* __restrict__ ps,
                                                       const float* __restrict__ ct,
                                                       float* __restrict__ out) {
    __shared__ float red[256];
    const int t = threadIdx.x;
    const int i = blockIdx.x * 256 + t;
    const float lse = logf(se[i]) + MAXOFF;
    red[t] = lse - ps[i] / fmaxf(ct[i], 1.0f);
    __syncthreads();
    for (int s = 128; s > 0; s >>= 1) {
        if (t < s) red[t] += red[t + s];
        __syncthreads();
    }
    if (t == 0) atomicAdd(out, red[0] * (1.0f / (float)BN_));
}

extern "C" void kernel_launch(void* const* d_in, const int* in_sizes, int n_in,
                              void* d_out, int out_size, void* d_ws, size_t ws_size,
                              hipStream_t stream) {
    const float* emb  = (const float*)d_in[0];
    const int*   mask = (const int*)d_in[1];
    float* out = (float*)d_out;

    char* ws = (char*)d_ws;
    unsigned short* ebf = (unsigned short*)ws;                       // 8 MB
    unsigned long long* pkll = (unsigned long long*)(ws + (size_t)8 * 1024 * 1024);  // 8 MB packed mask
    float* se = (float*)(ws + (size_t)16 * 1024 * 1024);
    float* ps = se + BN_;
    float* ct = ps + BN_;

    hipMemsetAsync(se, 0, (size_t)3 * BN_ * sizeof(float), stream);
    hipMemsetAsync(out, 0, sizeof(float), stream);
    normpack_kernel<<<2048 + BN_, 256, 0, stream>>>(emb, mask, ebf, pkll);
    infonce_main<<<2080, 256, 0, stream>>>(ebf, (const unsigned*)pkll, se, ps, ct);
    finalize_kernel<<<BN_ / 256, 256, 0, stream>>>(se, ps, ct, out);
}

// Round 5
// 174.372 us; speedup vs baseline: 1.7839x; 1.1470x over previous
//
#include <hip/hip_runtime.h>
#include <hip/hip_bf16.h>

// Problem constants (B=8192, D=512 from reference setup_inputs)
#define BN_ 8192
#define DK_ 512
#define TEMP_INV 14.2857142857142857f   // 1/0.07
#define LOG2E_ 1.44269504088896f
#define MAXOFF 15.0f                    // fixed lse offset; |sim| < 14.29 (unit vectors)

typedef __bf16 bf16x8 __attribute__((ext_vector_type(8)));
typedef float f32x4 __attribute__((ext_vector_type(4)));

__device__ inline unsigned short f2bf(float f) {
    unsigned u = __float_as_uint(f);
    return (unsigned short)((u + 0x7FFFu + ((u >> 16) & 1u)) >> 16);
}

// ---------- Kernel 1: fused {L2-normalize -> bf16} + {mask -> bit-pack} ----------
// blocks 0..2047: norm (4 rows each). blocks 2048..10239: pack one mask row each.
// Pack: all 32 row-words preloaded (32 loads in flight/thread) -> BW-bound, not latency.
__global__ __launch_bounds__(256) void normpack_kernel(
    const float* __restrict__ emb, const int* __restrict__ mask,
    unsigned short* __restrict__ ebf, unsigned long long* __restrict__ pk) {
    const int t = threadIdx.x;
    if (blockIdx.x < 2048) {
        const int row  = blockIdx.x * 4 + (t >> 6);
        const int lane = t & 63;
        const float4* src = reinterpret_cast<const float4*>(emb + (size_t)row * DK_);
        float4 v0 = src[lane];
        float4 v1 = src[lane + 64];
        float ss = v0.x*v0.x + v0.y*v0.y + v0.z*v0.z + v0.w*v0.w
                 + v1.x*v1.x + v1.y*v1.y + v1.z*v1.z + v1.w*v1.w;
#pragma unroll
        for (int off = 1; off < 64; off <<= 1) ss += __shfl_xor(ss, off, 64);
        const float scale = 1.0f / fmaxf(sqrtf(ss), 1e-12f);
        uint2 o0, o1;
        o0.x = (unsigned)f2bf(v0.x * scale) | ((unsigned)f2bf(v0.y * scale) << 16);
        o0.y = (unsigned)f2bf(v0.z * scale) | ((unsigned)f2bf(v0.w * scale) << 16);
        o1.x = (unsigned)f2bf(v1.x * scale) | ((unsigned)f2bf(v1.y * scale) << 16);
        o1.y = (unsigned)f2bf(v1.z * scale) | ((unsigned)f2bf(v1.w * scale) << 16);
        uint2* dst = reinterpret_cast<uint2*>(ebf + (size_t)row * DK_);
        dst[lane]      = o0;
        dst[lane + 64] = o1;
    } else {
        const int p    = blockIdx.x - 2048;          // mask row
        const int lane = t & 63;
        const int w    = t >> 6;
        const int* src = mask + (size_t)p * BN_;
        int v[32];
#pragma unroll
        for (int it = 0; it < 32; ++it) v[it] = src[it * 256 + t];  // 32 loads in flight
#pragma unroll
        for (int it = 0; it < 32; ++it) {
            const unsigned long long bal = __ballot(v[it] != 0);
            if (lane == 0) pk[(size_t)p * 128 + it * 4 + w] = bal;
        }
    }
}

// ---------- Kernel 2: symmetric 128x128 MFMA tiles (cb >= rb), 1-barrier dbuf ----------
// grid 2080; 256 threads = 4 waves (wr,wc), each a 64x64 quadrant of 16x16x32 frags.
// T3-minimum: STAGE(kt+1) into alternate buffer BEFORE computing kt; one barrier/kt.
__global__ __launch_bounds__(256) void infonce_main(
    const unsigned short* __restrict__ ebf,
    const unsigned* __restrict__ pk,
    float* __restrict__ se, float* __restrict__ ps, float* __restrict__ ct) {

    __shared__ unsigned short As[2][128 * 64];
    __shared__ unsigned short Bs[2][128 * 64];
    __shared__ uint4 pmS[256];        // [0..127] rb-rows x cb-cols bits; [128..255] transpose
    __shared__ float red3[3][128];    // row-partials (rb-block rows)
    __shared__ float redc[3][128];    // col-partials (cb-block rows)

    const int t    = threadIdx.x;
    const int lane = t & 63;
    const int wid  = t >> 6;
    const int wr   = wid >> 1;
    const int wc   = wid & 1;

    // triangular decode: bid -> (rb, cb) with cb >= rb; base(r) = 64r - r(r-1)/2
    const int bid = blockIdx.x;
    int rb = (int)((129.0f - sqrtf(16641.0f - 8.0f * (float)bid)) * 0.5f);
    while (64 * (rb + 1) - ((rb + 1) * rb) / 2 <= bid) ++rb;
    while (64 * rb - (rb * (rb - 1)) / 2 > bid) --rb;
    const int cb = rb + (bid - (64 * rb - (rb * (rb - 1)) / 2));
    const bool offd = (rb != cb);

    if (t < 128) {
        red3[0][t] = 0.f; red3[1][t] = 0.f; red3[2][t] = 0.f;
        redc[0][t] = 0.f; redc[1][t] = 0.f; redc[2][t] = 0.f;
    }
    const uint4* pk4 = reinterpret_cast<const uint4*>(pk);
    pmS[t] = (t < 128) ? pk4[(size_t)(rb * 128 + t) * 64 + cb]
                       : pk4[(size_t)(cb * 128 + (t - 128)) * 64 + rb];

    f32x4 acc[4][4] = {};

    // ebf staging map: thread t -> row t/8 (of 32), 16B chunk (t%8) within 64-elem k-row
    const int sr = t >> 3;
    const int sc = (t & 7) * 8;
    const size_t arow0 = (size_t)(rb * 128 + sr) * DK_ + sc;
    const size_t brow0 = (size_t)(cb * 128 + sr) * DK_ + sc;

    const int r16 = lane & 15;
    const int kg  = (lane >> 4) * 8;

#define STAGE(buf, kt)                                                                     \
    {                                                                                      \
        const int k0_ = (kt) * 64;                                                         \
        _Pragma("unroll")                                                                  \
        for (int s = 0; s < 4; ++s) {                                                      \
            __builtin_amdgcn_global_load_lds(                                              \
                (const __attribute__((address_space(1))) void*)(ebf + arow0 + (size_t)s * 32 * DK_ + k0_), \
                (__attribute__((address_space(3))) void*)(&As[buf][0] + s * 2048 + t * 8), \
                16, 0, 0);                                                                 \
        }                                                                                  \
        _Pragma("unroll")                                                                  \
        for (int s = 0; s < 4; ++s) {                                                      \
            __builtin_amdgcn_global_load_lds(                                              \
                (const __attribute__((address_space(1))) void*)(ebf + brow0 + (size_t)s * 32 * DK_ + k0_), \
                (__attribute__((address_space(3))) void*)(&Bs[buf][0] + s * 2048 + t * 8), \
                16, 0, 0);                                                                 \
        }                                                                                  \
    }

    STAGE(0, 0);
    __syncthreads();   // drain prologue loads (+ pmS stores)

#pragma unroll
    for (int kt = 0; kt < 8; ++kt) {
        const int b = kt & 1;
        if (kt < 7) STAGE(b ^ 1, kt + 1);   // issue next tile BEFORE compute (T3 min)

#pragma unroll
        for (int ks = 0; ks < 2; ++ks) {
            bf16x8 af[4], bfr[4];
#pragma unroll
            for (int fm = 0; fm < 4; ++fm)
                af[fm] = *reinterpret_cast<const bf16x8*>(&As[b][0] + (wr * 64 + fm * 16 + r16) * 64 + ks * 32 + kg);
#pragma unroll
            for (int fn = 0; fn < 4; ++fn)
                bfr[fn] = *reinterpret_cast<const bf16x8*>(&Bs[b][0] + (wc * 64 + fn * 16 + r16) * 64 + ks * 32 + kg);
#pragma unroll
            for (int fm = 0; fm < 4; ++fm)
#pragma unroll
                for (int fn = 0; fn < 4; ++fn)
                    acc[fm][fn] = __builtin_amdgcn_mfma_f32_16x16x32_bf16(af[fm], bfr[fn], acc[fm][fn], 0, 0, 0);
        }
        __syncthreads();   // one barrier/kt: readers done + next-tile loads drained
    }
#undef STAGE

    // ---- epilogue (verbatim from r4, passing) ----
    // C/D layout (16x16x32): col = lane&15, row = (lane>>4)*4 + reg
    const float C1 = TEMP_INV * LOG2E_;
    const float C2 = -MAXOFF * LOG2E_;
    const int c0 = cb * 128 + wc * 64;

    uint2 cw[4];
    if (offd) {
#pragma unroll
        for (int fn = 0; fn < 4; ++fn) {
            const int lj = wc * 64 + fn * 16 + (lane & 15);
            const uint4 v = pmS[128 + lj];
            cw[fn].x = wr ? v.z : v.x;
            cw[fn].y = wr ? v.w : v.y;
        }
    }
    float colL[4] = {0.f, 0.f, 0.f, 0.f};
    float colP[4] = {0.f, 0.f, 0.f, 0.f};

#pragma unroll
    for (int fm = 0; fm < 4; ++fm) {
#pragma unroll
        for (int q = 0; q < 4; ++q) {
            const int li = wr * 64 + fm * 16 + ((lane >> 4) << 2) + q;
            const int i  = rb * 128 + li;
            const uint4 rv = pmS[li];
            const unsigned r0 = wc ? rv.z : rv.x;
            const unsigned r1 = wc ? rv.w : rv.y;
            float lsep = 0.f, posp = 0.f;
#pragma unroll
            for (int fn = 0; fn < 4; ++fn) {
                const int j = c0 + fn * 16 + (lane & 15);
                const float a = acc[fm][fn][q];
                const bool diag = (i == j);
                const float ex = diag ? 0.0f : exp2f(fmaf(a, C1, C2));
                lsep += ex;
                const unsigned w = (fn < 2) ? r0 : r1;
                const bool p = (((w >> ((fn & 1) * 16 + (lane & 15))) & 1u) != 0u) && (!diag);
                posp += p ? a * TEMP_INV : 0.0f;
                if (offd) {
                    colL[fn] += ex;   // symmetric credit: sim(j,i) == sim(i,j)
                    const unsigned cwv = (fm < 2) ? cw[fn].x : cw[fn].y;
                    const int cbit = (fm & 1) * 16 + ((lane >> 4) << 2) + q;
                    colP[fn] += ((cwv >> cbit) & 1u) ? a * TEMP_INV : 0.0f;
                }
            }
#pragma unroll
            for (int off = 1; off < 16; off <<= 1) {
                lsep += __shfl_xor(lsep, off, 64);
                posp += __shfl_xor(posp, off, 64);
            }
            if ((lane & 15) == 0) {
                float cnt = (float)(__popc(r0) + __popc(r1));
                if (i >= c0 && i < c0 + 64) {
                    const int d = i - c0;
                    cnt -= (float)((d < 32 ? (r0 >> d) : (r1 >> (d - 32))) & 1u);
                }
                atomicAdd(&red3[0][li], lsep);
                atomicAdd(&red3[1][li], posp);
                atomicAdd(&red3[2][li], cnt);
            }
        }
    }

    if (offd) {
#pragma unroll
        for (int fn = 0; fn < 4; ++fn) {
            float L = colL[fn], P = colP[fn];
            L += __shfl_xor(L, 16, 64); L += __shfl_xor(L, 32, 64);
            P += __shfl_xor(P, 16, 64); P += __shfl_xor(P, 32, 64);
            if ((lane >> 4) == 0) {
                const int lj = wc * 64 + fn * 16 + lane;
                const float cnt = (float)(__popc(cw[fn].x) + __popc(cw[fn].y));
                atomicAdd(&redc[0][lj], L);
                atomicAdd(&redc[1][lj], P);
                atomicAdd(&redc[2][lj], cnt);
            }
        }
    }
    __syncthreads();
    if (t < 128) {
        const int i = rb * 128 + t;
        atomicAdd(&se[i], red3[0][t]);
        atomicAdd(&ps[i], red3[1][t]);
        atomicAdd(&ct[i], red3[2][t]);
    } else if (offd) {
        const int j = cb * 128 + (t - 128);
        atomicAdd(&se[j], redc[0][t - 128]);
        atomicAdd(&ps[j], redc[1][t - 128]);
        atomicAdd(&ct[j], redc[2][t - 128]);
    }
}

// ---------------- Kernel 3: finalize scalar loss (32 blocks) ----------------
__global__ __launch_bounds__(256) void finalize_kernel(const float* __restrict__ se,
                                                       const float* __restrict__ ps,
                                                       const float* __restrict__ ct,
                                                       float* __restrict__ out) {
    __shared__ float red[256];
    const int t = threadIdx.x;
    const int i = blockIdx.x * 256 + t;
    const float lse = logf(se[i]) + MAXOFF;
    red[t] = lse - ps[i] / fmaxf(ct[i], 1.0f);
    __syncthreads();
    for (int s = 128; s > 0; s >>= 1) {
        if (t < s) red[t] += red[t + s];
        __syncthreads();
    }
    if (t == 0) atomicAdd(out, red[0] * (1.0f / (float)BN_));
}

extern "C" void kernel_launch(void* const* d_in, const int* in_sizes, int n_in,
                              void* d_out, int out_size, void* d_ws, size_t ws_size,
                              hipStream_t stream) {
    const float* emb  = (const float*)d_in[0];
    const int*   mask = (const int*)d_in[1];
    float* out = (float*)d_out;

    char* ws = (char*)d_ws;
    unsigned short* ebf = (unsigned short*)ws;                       // 8 MB
    unsigned long long* pkll = (unsigned long long*)(ws + (size_t)8 * 1024 * 1024);  // 8 MB packed mask
    float* se = (float*)(ws + (size_t)16 * 1024 * 1024);
    float* ps = se + BN_;
    float* ct = ps + BN_;

    hipMemsetAsync(se, 0, (size_t)3 * BN_ * sizeof(float), stream);
    hipMemsetAsync(out, 0, sizeof(float), stream);
    normpack_kernel<<<2048 + BN_, 256, 0, stream>>>(emb, mask, ebf, pkll);
    infonce_main<<<2080, 256, 0, stream>>>(ebf, (const unsigned*)pkll, se, ps, ct);
    finalize_kernel<<<BN_ / 256, 256, 0, stream>>>(se, ps, ct, out);
}

// Round 6
// 133.648 us; speedup vs baseline: 2.3274x; 1.3047x over previous
//
#include <hip/hip_runtime.h>
#include <hip/hip_bf16.h>

// Problem constants (B=8192, D=512 from reference setup_inputs)
#define BN_ 8192
#define DK_ 512
#define TEMP_INV 14.2857142857142857f   // 1/0.07
#define LOG2E_ 1.44269504088896f
#define MAXOFF 15.0f                    // fixed lse offset; |sim| < 14.29 (unit vectors)

typedef __bf16 bf16x8 __attribute__((ext_vector_type(8)));
typedef float f32x4 __attribute__((ext_vector_type(4)));

__device__ inline unsigned short f2bf(float f) {
    unsigned u = __float_as_uint(f);
    return (unsigned short)((u + 0x7FFFu + ((u >> 16) & 1u)) >> 16);
}

// ---------------- Kernel 1: L2-normalize rows, write bf16 ----------------
__global__ __launch_bounds__(256) void norm_kernel(const float* __restrict__ emb,
                                                   unsigned short* __restrict__ ebf) {
    const int row  = blockIdx.x * 4 + (threadIdx.x >> 6);
    const int lane = threadIdx.x & 63;
    const float4* src = reinterpret_cast<const float4*>(emb + (size_t)row * DK_);
    float4 v0 = src[lane];
    float4 v1 = src[lane + 64];
    float ss = v0.x*v0.x + v0.y*v0.y + v0.z*v0.z + v0.w*v0.w
             + v1.x*v1.x + v1.y*v1.y + v1.z*v1.z + v1.w*v1.w;
#pragma unroll
    for (int off = 1; off < 64; off <<= 1) ss += __shfl_xor(ss, off, 64);
    const float scale = 1.0f / fmaxf(sqrtf(ss), 1e-12f);
    uint2 o0, o1;
    o0.x = (unsigned)f2bf(v0.x * scale) | ((unsigned)f2bf(v0.y * scale) << 16);
    o0.y = (unsigned)f2bf(v0.z * scale) | ((unsigned)f2bf(v0.w * scale) << 16);
    o1.x = (unsigned)f2bf(v1.x * scale) | ((unsigned)f2bf(v1.y * scale) << 16);
    o1.y = (unsigned)f2bf(v1.z * scale) | ((unsigned)f2bf(v1.w * scale) << 16);
    uint2* dst = reinterpret_cast<uint2*>(ebf + (size_t)row * DK_);
    dst[lane]      = o0;
    dst[lane + 64] = o1;
}

// ---------------- Kernel 2: fused 128x128 MFMA tile, full grid ----------------
// 256 threads = 4 waves (wr,wc), each a 64x64 quadrant of 16x16x32 frags.
// SWAPPED mfma operands: acc[fm][fn] = mfma(bfr[fn], af[fm]) so per lane
//   i_local = fm*16 + (lane&15)  (row: fixed per fm)
//   j_local = fn*16 + (lane>>4)*4 + reg  (16 cols in-lane)
// -> row sums are in-lane + 2 butterflies, no 16-lane reduction chains.
// Mask: raw int4 patch loads folded into the staging phase (drained by the same
// vmcnt(0)+barrier as ebf staging), bit-packed to a 2KB LDS tile for the epilogue.
__global__ __launch_bounds__(256) void infonce_main(
    const unsigned short* __restrict__ ebf,
    const int* __restrict__ mask,
    float* __restrict__ se, float* __restrict__ ps, float* __restrict__ ct) {

    __shared__ unsigned short As[128 * 64];       // 16KB
    __shared__ unsigned short Bs[128 * 64];       // 16KB
    __shared__ unsigned char  pmB[128 * 16];      // 2KB mask bit-tile (row-major, 16B/row)
    __shared__ float red2[2][128];                // 1KB row partials {lse, pos}

    const int t    = threadIdx.x;
    const int lane = t & 63;
    const int wid  = t >> 6;
    const int wr   = wid >> 1;
    const int wc   = wid & 1;
    const int rb   = blockIdx.x;
    const int cb   = blockIdx.y;

    if (t < 128) { red2[0][t] = 0.f; red2[1][t] = 0.f; }

    f32x4 acc[4][4] = {};

    // ebf staging map: thread t -> row t/8 (of 32), 16B chunk (t%8) within 64-elem k-row
    const int sr = t >> 3;
    const int sc = (t & 7) * 8;
    const size_t arow0 = (size_t)(rb * 128 + sr) * DK_ + sc;
    const size_t brow0 = (size_t)(cb * 128 + sr) * DK_ + sc;

    // mask staging map: thread t -> patch row t>>4 (of 16 per kt), cols (t&15)*8..+7
    const int mr = t >> 4;
    const int mc = t & 15;
    const int* mbase = mask + (size_t)(rb * 128 + mr) * BN_ + cb * 128 + mc * 8;

    const int r16 = lane & 15;
    const int kg  = (lane >> 4) * 8;

#pragma unroll
    for (int kt = 0; kt < 8; ++kt) {
        const int k0 = kt * 64;
#pragma unroll
        for (int s = 0; s < 4; ++s) {
            __builtin_amdgcn_global_load_lds(
                (const __attribute__((address_space(1))) void*)(ebf + arow0 + (size_t)s * 32 * DK_ + k0),
                (__attribute__((address_space(3))) void*)(As + s * 2048 + t * 8),
                16, 0, 0);
        }
#pragma unroll
        for (int s = 0; s < 4; ++s) {
            __builtin_amdgcn_global_load_lds(
                (const __attribute__((address_space(1))) void*)(ebf + brow0 + (size_t)s * 32 * DK_ + k0),
                (__attribute__((address_space(3))) void*)(Bs + s * 2048 + t * 8),
                16, 0, 0);
        }
        // mask patch rows kt*16..+15: 2 coalesced int4 loads, same vmcnt stream
        const int4* mp = reinterpret_cast<const int4*>(mbase + (size_t)kt * 16 * BN_);
        const int4 mv0 = mp[0];
        const int4 mv1 = mp[1];

        __syncthreads();   // vmcnt(0) drain: LDS tiles + mv regs all ready

        // pack 8 mask bits -> bit-tile (overlaps the MFMA phase)
        {
            unsigned by = (unsigned)(mv0.x != 0)        | ((unsigned)(mv0.y != 0) << 1)
                        | ((unsigned)(mv0.z != 0) << 2) | ((unsigned)(mv0.w != 0) << 3)
                        | ((unsigned)(mv1.x != 0) << 4) | ((unsigned)(mv1.y != 0) << 5)
                        | ((unsigned)(mv1.z != 0) << 6) | ((unsigned)(mv1.w != 0) << 7);
            pmB[(kt * 16 + mr) * 16 + mc] = (unsigned char)by;
        }

#pragma unroll
        for (int ks = 0; ks < 2; ++ks) {
            bf16x8 af[4], bfr[4];
#pragma unroll
            for (int fm = 0; fm < 4; ++fm)
                af[fm] = *reinterpret_cast<const bf16x8*>(As + (wr * 64 + fm * 16 + r16) * 64 + ks * 32 + kg);
#pragma unroll
            for (int fn = 0; fn < 4; ++fn)
                bfr[fn] = *reinterpret_cast<const bf16x8*>(Bs + (wc * 64 + fn * 16 + r16) * 64 + ks * 32 + kg);
#pragma unroll
            for (int fm = 0; fm < 4; ++fm)
#pragma unroll
                for (int fn = 0; fn < 4; ++fn)
                    acc[fm][fn] = __builtin_amdgcn_mfma_f32_16x16x32_bf16(bfr[fn], af[fm], acc[fm][fn], 0, 0, 0);
        }
        __syncthreads();   // LDS consumed; safe to restage (also orders pmB for epilogue)
    }

    // ---- epilogue: swapped layout -> in-lane row sums ----
    const float C1 = TEMP_INV * LOG2E_;
    const float C2 = -MAXOFF * LOG2E_;
    const bool  db  = (rb == cb);
    const int   gq4 = (lane >> 4) * 4;

#pragma unroll
    for (int fm = 0; fm < 4; ++fm) {
        const int li = wr * 64 + fm * 16 + (lane & 15);
        const uint4 rv = *reinterpret_cast<const uint4*>(pmB + li * 16);
        const unsigned w0 = wc ? rv.z : rv.x;   // this wave's 64-col window, bits 0..31
        const unsigned w1 = wc ? rv.w : rv.y;   // bits 32..63
        float lsep = 0.f, posp = 0.f;
#pragma unroll
        for (int fn = 0; fn < 4; ++fn) {
            const unsigned wsel = (fn < 2) ? w0 : w1;
#pragma unroll
            for (int rg = 0; rg < 4; ++rg) {
                const float a = acc[fm][fn][rg];
                // diag: needs rb==cb, wr==wc, fm==fn, (lane&15)==gq4+rg
                const bool dg = db && (wr == wc) && (fm == fn) && ((lane & 15) == gq4 + rg);
                const float ex = dg ? 0.0f : exp2f(fmaf(a, C1, C2));
                lsep += ex;
                const bool p = (((wsel >> ((fn & 1) * 16 + gq4 + rg)) & 1u) != 0u) && !dg;
                posp += p ? a : 0.0f;
            }
        }
        lsep += __shfl_xor(lsep, 16, 64); lsep += __shfl_xor(lsep, 32, 64);
        posp += __shfl_xor(posp, 16, 64); posp += __shfl_xor(posp, 32, 64);
        if ((lane >> 4) == 0) {
            atomicAdd(&red2[0][li], lsep);                 // ds atomic, cross-wc merge
            atomicAdd(&red2[1][li], posp * TEMP_INV);
        }
    }
    __syncthreads();
    if (t < 128) {
        const uint4 rv = *reinterpret_cast<const uint4*>(pmB + t * 16);
        float cnt = (float)(__popc(rv.x) + __popc(rv.y) + __popc(rv.z) + __popc(rv.w));
        if (db) {   // remove diagonal bit from count (diag col == local row t)
            const unsigned wsel = (t < 64) ? ((t < 32) ? rv.x : rv.y)
                                           : ((t < 96) ? rv.z : rv.w);
            cnt -= (float)((wsel >> (t & 31)) & 1u);
        }
        const int i = rb * 128 + t;
        atomicAdd(&se[i], red2[0][t]);
        atomicAdd(&ps[i], red2[1][t]);
        atomicAdd(&ct[i], cnt);
    }
}

// ---------------- Kernel 3: finalize scalar loss (32 blocks) ----------------
__global__ __launch_bounds__(256) void finalize_kernel(const float* __restrict__ se,
                                                       const float* __restrict__ ps,
                                                       const float* __restrict__ ct,
                                                       float* __restrict__ out) {
    __shared__ float red[256];
    const int t = threadIdx.x;
    const int i = blockIdx.x * 256 + t;
    const float lse = logf(se[i]) + MAXOFF;
    red[t] = lse - ps[i] / fmaxf(ct[i], 1.0f);
    __syncthreads();
    for (int s = 128; s > 0; s >>= 1) {
        if (t < s) red[t] += red[t + s];
        __syncthreads();
    }
    if (t == 0) atomicAdd(out, red[0] * (1.0f / (float)BN_));
}

extern "C" void kernel_launch(void* const* d_in, const int* in_sizes, int n_in,
                              void* d_out, int out_size, void* d_ws, size_t ws_size,
                              hipStream_t stream) {
    const float* emb  = (const float*)d_in[0];
    const int*   mask = (const int*)d_in[1];
    float* out = (float*)d_out;

    char* ws = (char*)d_ws;
    unsigned short* ebf = (unsigned short*)ws;                  // 8 MB bf16 normalized
    float* se = (float*)(ws + (size_t)8 * 1024 * 1024);
    float* ps = se + BN_;
    float* ct = ps + BN_;

    hipMemsetAsync(se, 0, (size_t)3 * BN_ * sizeof(float), stream);
    hipMemsetAsync(out, 0, sizeof(float), stream);
    norm_kernel<<<BN_ / 4, 256, 0, stream>>>(emb, ebf);
    infonce_main<<<dim3(64, 64), 256, 0, stream>>>(ebf, mask, se, ps, ct);
    finalize_kernel<<<BN_ / 256, 256, 0, stream>>>(se, ps, ct, out);
}